// Round 6
// baseline (2234.563 us; speedup 1.0000x reference)
//
#include <hip/hip_runtime.h>
#include <stdint.h>
#include <stddef.h>

// Problem constants
#define VOCAB 50000
#define EMB   128
#define HID   256
#define G4    1024   // 4*HID
#define BATCH 512
#define SEQ   256
#define NCHAIN 1024  // 2 sequences * 512 batch

// ---------- workspace layout (bytes) ----------
#define OFF_TABLE  0UL
#define SZ_TABLE   (50000UL*1024UL*2UL)            // 102,400,000  bf16 gate table (permuted cols)
#define OFF_WHHF   (OFF_TABLE + SZ_TABLE)
#define SZ_WHHF    (512UL*512UL*2UL)               // 524,288      w_hh B-fragments bf16
#define OFF_WIHF   (OFF_WHHF + SZ_WHHF)
#define SZ_WIHF    (256UL*512UL*2UL)               // 262,144      w_ih B-fragments bf16
#define OFF_BCOMB  (OFF_WIHF + SZ_WIHF)
#define SZ_BCOMB   (1024UL*4UL)                    // combined bias (permuted)
#define OFF_WHIDT  (OFF_BCOMB + SZ_BCOMB)
#define SZ_WHIDT   (512UL*256UL*4UL)               // w_hid transposed [512][256] f32
#define OFF_HOUT   (OFF_WHIDT + SZ_WHIDT)
#define SZ_HOUT    (1024UL*256UL*4UL)              // final h per chain, f32
// total ~104.8 MB

typedef short bf16x8 __attribute__((ext_vector_type(8)));
typedef short bf16x4 __attribute__((ext_vector_type(4)));
typedef float f32x4  __attribute__((ext_vector_type(4)));
typedef float f32x2  __attribute__((ext_vector_type(2)));

__device__ __forceinline__ unsigned short f2bf(float f) {
  union { float f; uint32_t u; } v; v.f = f;
  uint32_t r = (v.u + 0x7FFFu + ((v.u >> 16) & 1u)) >> 16;
  return (unsigned short)r;
}
__device__ __forceinline__ float bf2f(unsigned short h) {
  union { float f; uint32_t u; } v; v.u = ((uint32_t)h) << 16; return v.f;
}
__device__ __forceinline__ float fast_exp2(float x) { return __builtin_amdgcn_exp2f(x); }
__device__ __forceinline__ float fast_rcp(float x)  { return __builtin_amdgcn_rcpf(x); }
#define LOG2E 1.4426950408889634f
__device__ __forceinline__ float sigm(float x) {
  return fast_rcp(1.0f + fast_exp2(-LOG2E * x));
}
__device__ __forceinline__ float tanh_(float x) {
  float e = fast_exp2(2.0f * LOG2E * x);     // exp(2x)
  return 1.0f - 2.0f * fast_rcp(e + 1.0f);   // (e-1)/(e+1)
}

// gate permutation: wave w (0..7) owns local gates i (0..127);
// original gate index = (i>>5)*256 + w*32 + (i&31)   (blocks: i,f,g,o for j in [w*32, w*32+32))
__device__ __forceinline__ int gperm(int w, int i) {
  return ((i >> 5) << 8) + (w << 5) + (i & 31);
}

// LDS swizzles (byte-XOR per G4 to break b128 same-bank columns). Index in ushorts.
__device__ __forceinline__ int hswz(int m, int k) {          // h tile: row stride 256 bf16
  return ((m * 512 + k * 2) ^ ((m & 7) << 4)) >> 1;
}
__device__ __forceinline__ int aswz(int row, int k) {        // emb tile: row stride 128 bf16
  return ((row * 256 + k * 2) ^ ((row & 7) << 4)) >> 1;
}

// Shared A/B k-placement bijection within each 32-wide k block (A and B use the SAME
// map so the MFMA contraction pairs identical true-k on both sides; dot products are
// permutation-invariant so the true HW k-map is irrelevant):
//   scatter by true k: k = hf*16 + v (hf=bit4, v=k&15) -> p = (v>>2)*8 + hf*4 + (v&3)
__device__ __forceinline__ int kplace(int k) {   // k in [0,32), returns p in [0,32)
  int v = k & 15, hf = (k >> 4) & 1;
  return ((v >> 2) << 3) + (hf << 2) + (v & 3);
}

// xg table column order within wave slice: storage pos = c0*8 + nt (nt = local n-tile
// = gate*2 + hf). Elementwise reads its 8 pre-activations as ONE b128 per chain.

// ============================================================================
// k0: pack w_hh / w_ih into MFMA B-fragment layout (bf16), combined bias, w_hid^T
// ============================================================================
__global__ __launch_bounds__(256) void k0_prep(
    const float* __restrict__ w_ih, const float* __restrict__ w_hh,
    const float* __restrict__ b_ih, const float* __restrict__ b_hh,
    const float* __restrict__ w_hid,
    unsigned short* __restrict__ whhf, unsigned short* __restrict__ wihf,
    float* __restrict__ bcomb, float* __restrict__ whidT)
{
  int idx = blockIdx.x * 256 + threadIdx.x;
  if (idx < 262144) {                       // whhf: 512 frags x 512 ushorts
    int f = idx >> 9, r = idx & 511, l = r >> 3, e = r & 7;
    int w = f >> 6, nt = (f >> 3) & 7, ks = f & 7;
    int n = gperm(w, nt * 16 + (l & 15));
    int k = ks * 32 + ((e >> 2) << 4) + ((l >> 4) << 2) + (e & 3);
    whhf[idx] = f2bf(w_hh[n * HID + k]);
  } else if (idx < 262144 + 131072) {       // wihf: 256 frags x 512
    int i2 = idx - 262144;
    int f = i2 >> 9, r = i2 & 511, l = r >> 3, e = r & 7;
    int ks = f & 3, nt = (f >> 2) & 7, w = f >> 5;
    int n = gperm(w, nt * 16 + (l & 15));
    int k = ks * 32 + ((e >> 2) << 4) + ((l >> 4) << 2) + (e & 3);
    wihf[i2] = f2bf(w_ih[n * EMB + k]);
  } else if (idx < 262144 + 131072 + 1024) {
    int i2 = idx - (262144 + 131072);
    int w = i2 >> 7, ii = i2 & 127;
    int g = gperm(w, ii);
    bcomb[i2] = b_ih[g] + b_hh[g];
  } else if (idx < 262144 + 131072 + 1024 + 131072) {
    int i2 = idx - (262144 + 131072 + 1024);
    int k = i2 >> 8, rr = i2 & 255;
    whidT[i2] = w_hid[rr * 512 + k];        // w_hid [256][512] -> [512][256]
  }
}

// ============================================================================
// k1: gate table GEMM: table[v][p] = emb[v] . w_ih[G(p)] + bcomb[p]   (bf16 out)
//     M=50000 rows (64/block), N=1024 permuted cols, K=128.
// ============================================================================
__global__ __launch_bounds__(256, 4) void k1_table(
    const float* __restrict__ emb, const unsigned short* __restrict__ wihf,
    const float* __restrict__ bcomb, unsigned short* __restrict__ table2)
{
  __shared__ unsigned short a_lds[64 * 128];      // swizzled + k-placed bf16
  __shared__ unsigned short ostage[4 * 16 * 136]; // per-wave staging, padded rows
  const int tid = threadIdx.x;
  const int w = tid >> 6, l = tid & 63, r0 = l >> 4, c0 = l & 15;
  const int v0 = blockIdx.x * 64;

  // stage 64 emb rows as bf16, scattered into the SHARED k-placement map
  for (int idx = tid; idx < 8192; idx += 256) {
    int row = idx >> 7, k = idx & 127;
    int gr = v0 + row; if (gr >= VOCAB) gr = VOCAB - 1;
    float x = emb[(size_t)gr * EMB + k];
    int p = (k & ~31) + kplace(k & 31);
    a_lds[aswz(row, p)] = f2bf(x);
  }
  __syncthreads();

  bf16x8 af[4];
#pragma unroll
  for (int ks = 0; ks < 4; ++ks)
    af[ks] = *(const bf16x8*)&a_lds[aswz(w * 16 + c0, ks * 32 + r0 * 8)];

  unsigned short* ost = &ostage[w * 2176];
#pragma unroll 1
  for (int nb = 0; nb < 8; ++nb) {
    f32x4 acc[8];
#pragma unroll
    for (int nt = 0; nt < 8; ++nt) acc[nt] = (f32x4){0.f, 0.f, 0.f, 0.f};
#pragma unroll
    for (int ks = 0; ks < 4; ++ks) {
#pragma unroll
      for (int nt = 0; nt < 8; ++nt) {
        bf16x8 bv = *(const bf16x8*)(wihf + ((((nb * 8 + nt) * 4) + ks) << 9) + (l << 3));
        acc[nt] = __builtin_amdgcn_mfma_f32_16x16x32_bf16(af[ks], bv, acc[nt], 0, 0, 0);
      }
    }
    // column order: local gate (nt,c0) stored at pos c0*8 + nt
#pragma unroll
    for (int nt = 0; nt < 8; ++nt) {
      float bias = bcomb[nb * 128 + nt * 16 + c0];
#pragma unroll
      for (int reg = 0; reg < 4; ++reg)
        ost[(r0 * 4 + reg) * 136 + c0 * 8 + nt] = f2bf(acc[nt][reg] + bias);
    }
    asm volatile("s_waitcnt lgkmcnt(0)" ::: "memory");
#pragma unroll
    for (int i = 0; i < 4; ++i) {
      int idx = i * 64 + l;
      int row = idx >> 4, seg = idx & 15;
      int v = v0 + w * 16 + row;
      if (v < VOCAB)
        *(bf16x8*)(table2 + (size_t)v * 1024 + nb * 128 + seg * 8) =
            *(const bf16x8*)&ost[row * 136 + seg * 8];
    }
    __syncthreads();
  }
}

// ============================================================================
// k2: the recurrence. 128 blocks x 512 threads (8 waves). Block owns 8 chains
//     (M-rows 8..15 of the MFMA tile are REPLICAS of chains 0..7: A is read as
//     h_lds[row&7] -- same-address LDS broadcast, free). Duplicated C rows are
//     exploited to split elementwise: lane group r0 handles (hf=r0>>1, cl=r0&1)
//     -> 4 values x 4 gates per lane, all 64 lanes busy.
//     Per-CU MFMA issue is invariant in chains/block, so 2x blocks halves the
//     per-CU elementwise/LDS/gather while doubling active CUs (64 -> 128).
//     Weight residency per wave (frag f = nt*8+ks, 64 frags, 1 KB each):
//       nt 0..3            (32 frags): VGPR/AGPR-resident (128 regs)
//       nt4 all, nt5 ks0-4 (13 frags): LDS-resident (106 KB)
//       nt5 ks5-7, nt6, nt7 (19 frags): streamed from L2, 3-slot rotating
//                                       reg buffer, 2-ks lookahead
// ============================================================================
__global__ __launch_bounds__(512) void k2_lstm(
    const int* __restrict__ s1, const int* __restrict__ s2,
    const unsigned short* __restrict__ table2,
    const unsigned short* __restrict__ whhf,
    float* __restrict__ h_out)
{
  __shared__ unsigned short h_lds[8 * 256];       // 4 KB  swizzled + k-placed bf16
  __shared__ unsigned short tok_lds[8 * 256];     // 4 KB  tokens as u16
  __shared__ unsigned short xg_lds[8 * 8 * 136];  // 17.4 KB per-wave xg slices
  __shared__ unsigned short w_lds[8 * 13 * 512];  // 106 KB  13 weight frags/wave

  const int tid = threadIdx.x;
  const int w = tid >> 6, l = tid & 63;
  const int r0 = l >> 4, c0 = l & 15;
  const int blk = blockIdx.x;
  const int chain_g = l >> 3;         // gather: 8 lanes per chain
  const int seg = l & 7;
  const int hf = r0 >> 1;             // elementwise: j-half this lane handles
  const int cl = r0 & 1;              // elementwise: chain-half this lane handles

  // preload tokens (u16) + zero h  (both arrays are 2048 entries)
  for (int idx = tid; idx < 2048; idx += 512) {
    int chain = blk * 8 + (idx >> 8);
    const int* sp = (chain >= 512) ? s2 : s1;
    tok_lds[idx] = (unsigned short)sp[(chain & 511) * SEQ + (idx & 255)];
    h_lds[idx] = 0;
  }

  const unsigned short* whW = whhf + w * 32768;  // this wave's 64 frags
  unsigned short* wl = &w_lds[w * 6656];

  // stage LDS-resident frags: j<8 -> nt4 ks=j ; j>=8 -> nt5 ks=j-8 (ks0..4)
#pragma unroll
  for (int j = 0; j < 13; ++j) {
    int frag = (j < 8) ? (4 * 8 + j) : (5 * 8 + (j - 8));
    bf16x8 v = *(const bf16x8*)(whW + (frag << 9) + (l << 3));
    *(bf16x8*)&wl[j * 512 + (l << 3)] = v;
  }

  // VGPR/AGPR-resident frags: nt 0..3, all ks (128 regs)
  bf16x8 whr[32];
#pragma unroll
  for (int f = 0; f < 32; ++f)
    whr[f] = *(const bf16x8*)(whW + (f << 9) + (l << 3));

  __syncthreads();

  // streamed rotating buffer: batch p (=ks p): slot p%3.
  // slot contents: [0]=nt6 ksp, [1]=nt7 ksp, [2]=nt5 ksp (p>=5 only)
  bf16x8 sbuf[3][3];
#define ISSUE_BATCH(P, S)                                                         \
  do {                                                                            \
    sbuf[S][0] = *(const bf16x8*)(whW + ((6 * 8 + (P)) << 9) + (l << 3));         \
    sbuf[S][1] = *(const bf16x8*)(whW + ((7 * 8 + (P)) << 9) + (l << 3));         \
    if ((P) >= 5)                                                                 \
      sbuf[S][2] = *(const bf16x8*)(whW + ((5 * 8 + (P)) << 9) + (l << 3));       \
  } while (0)

  // prologue: first gather (2 b128/lane) + first two stream batches
  bf16x8 X0, X1;
  {
    int tok0 = tok_lds[chain_g * 256 + 0];
    const unsigned short* xr = table2 + (size_t)tok0 * 1024 + w * 128;
    X0 = *(const bf16x8*)(xr + seg * 8);
    X1 = *(const bf16x8*)(xr + (seg + 8) * 8);
  }
  ISSUE_BATCH(0, 0);
  ISSUE_BATCH(1, 1);

  float c_st[4], hv[4];
#pragma unroll
  for (int i = 0; i < 4; ++i) { c_st[i] = 0.f; hv[i] = 0.f; }

#pragma unroll 1
  for (int t = 0; t < SEQ; ++t) {
    // store this step's xg into per-wave LDS slice
    {
      int base = w * 1088 + chain_g * 136;
      *(bf16x8*)&xg_lds[base + seg * 8] = X0;
      *(bf16x8*)&xg_lds[base + (seg + 8) * 8] = X1;
    }
    // issue NEXT step's gather now -- covered by the whole MFMA loop
    if (t + 1 < SEQ) {
      int tok = tok_lds[chain_g * 256 + (t + 1)];
      const unsigned short* xr = table2 + (size_t)tok * 1024 + w * 128;
      X0 = *(const bf16x8*)(xr + seg * 8);
      X1 = *(const bf16x8*)(xr + (seg + 8) * 8);
    }

    f32x4 acc[8];
#pragma unroll
    for (int nt = 0; nt < 8; ++nt) acc[nt] = (f32x4){0.f, 0.f, 0.f, 0.f};

#pragma unroll
    for (int p = 0; p < 8; ++p) {
      if (p + 2 <= 7) { ISSUE_BATCH(p + 2, (p + 2) % 3); }
      // A row (lane&15) -> chain (row&7); rows 8..15 replicate = same-addr read
      bf16x8 av = *(const bf16x8*)&h_lds[hswz(c0 & 7, p * 32 + r0 * 8)];
      acc[0] = __builtin_amdgcn_mfma_f32_16x16x32_bf16(av, whr[0 * 8 + p], acc[0], 0, 0, 0);
      acc[1] = __builtin_amdgcn_mfma_f32_16x16x32_bf16(av, whr[1 * 8 + p], acc[1], 0, 0, 0);
      acc[2] = __builtin_amdgcn_mfma_f32_16x16x32_bf16(av, whr[2 * 8 + p], acc[2], 0, 0, 0);
      acc[3] = __builtin_amdgcn_mfma_f32_16x16x32_bf16(av, whr[3 * 8 + p], acc[3], 0, 0, 0);
      {
        bf16x8 bv = *(const bf16x8*)&wl[p * 512 + (l << 3)];
        acc[4] = __builtin_amdgcn_mfma_f32_16x16x32_bf16(av, bv, acc[4], 0, 0, 0);
      }
      if (p < 5) {
        bf16x8 bv = *(const bf16x8*)&wl[(8 + p) * 512 + (l << 3)];
        acc[5] = __builtin_amdgcn_mfma_f32_16x16x32_bf16(av, bv, acc[5], 0, 0, 0);
      } else {
        acc[5] = __builtin_amdgcn_mfma_f32_16x16x32_bf16(av, sbuf[p % 3][2], acc[5], 0, 0, 0);
      }
      acc[6] = __builtin_amdgcn_mfma_f32_16x16x32_bf16(av, sbuf[p % 3][0], acc[6], 0, 0, 0);
      acc[7] = __builtin_amdgcn_mfma_f32_16x16x32_bf16(av, sbuf[p % 3][1], acc[7], 0, 0, 0);
    }

    // issue next step's first two stream batches (covered by elementwise+barriers)
    if (t + 1 < SEQ) {
      ISSUE_BATCH(0, 0);
      ISSUE_BATCH(1, 1);
    }

    // gates -> c,h. Lane (r0,c0) handles (hf=r0>>1, chains cl*4+q, j=w*32+hf*16+c0).
    // C row = r0*4+reg, chain = row&7 = cl*4+reg. Gate g at nt = g*2+hf.
    asm volatile("s_waitcnt lgkmcnt(0)" ::: "memory");
#pragma unroll
    for (int q = 0; q < 4; ++q) {
      int chain = cl * 4 + q;
      bf16x8 xv = *(const bf16x8*)&xg_lds[w * 1088 + chain * 136 + c0 * 8];
      float iv = sigm(acc[0 + hf][q] + bf2f((unsigned short)xv[0 + hf]));
      float fv = sigm(acc[2 + hf][q] + bf2f((unsigned short)xv[2 + hf]));
      float gv = tanh_(acc[4 + hf][q] + bf2f((unsigned short)xv[4 + hf]));
      float ov = sigm(acc[6 + hf][q] + bf2f((unsigned short)xv[6 + hf]));
      float c = fv * c_st[q] + iv * gv;
      c_st[q] = c;
      hv[q] = ov * tanh_(c);
    }

    __syncthreads();   // all waves done reading h(t-1)
#pragma unroll
    for (int q = 0; q < 4; ++q) {
      int m = cl * 4 + q;
      // original j = w*32 + hf*16 + c0 -> SHARED k-placement within block w
      int qk = (w << 5) + ((c0 >> 2) << 3) + (hf << 2) + (c0 & 3);
      h_lds[hswz(m, qk)] = f2bf(hv[q]);
    }
    __syncthreads();   // h(t) visible
  }

  // final h (f32, pre-rounding) -> h_out[chain][j]
#pragma unroll
  for (int q = 0; q < 4; ++q) {
    int chain = cl * 4 + q;
    int j = w * 32 + hf * 16 + c0;
    h_out[(size_t)(blk * 8 + chain) * HID + j] = hv[q];
  }
#undef ISSUE_BATCH
}

// ============================================================================
// k3: head: hidden = relu([h1,h2] @ w_hid^T + b_hid); out = hidden @ w_out^T + b_out
// ============================================================================
__global__ __launch_bounds__(256, 4) void k3_head(
    const float* __restrict__ h_out, const float* __restrict__ whidT,
    const float* __restrict__ b_hid, const float* __restrict__ w_out,
    const float* __restrict__ b_out, float* __restrict__ out)
{
  __shared__ float cat[8 * 512];
  __shared__ float hred[8 * 256];
  __shared__ float pred[4 * 24];
  const int tid = threadIdx.x;
  const int b0 = blockIdx.x * 8;

  for (int idx = tid; idx < 4096; idx += 256) {
    int r8 = idx >> 9, kk = idx & 511;
    float v = (kk < 256) ? h_out[(size_t)(b0 + r8) * HID + kk]
                         : h_out[(size_t)(512 + b0 + r8) * HID + (kk - 256)];
    cat[idx] = v;
  }
  __syncthreads();

  const int r = tid;
  float acc[8];
#pragma unroll
  for (int bb = 0; bb < 8; ++bb) acc[bb] = 0.f;
  for (int k = 0; k < 512; k += 4) {
    float w0 = whidT[(k + 0) * 256 + r];
    float w1 = whidT[(k + 1) * 256 + r];
    float w2 = whidT[(k + 2) * 256 + r];
    float w3 = whidT[(k + 3) * 256 + r];
#pragma unroll
    for (int bb = 0; bb < 8; ++bb) {
      f32x4 cv = *(const f32x4*)&cat[bb * 512 + k];
      acc[bb] += cv[0] * w0 + cv[1] * w1 + cv[2] * w2 + cv[3] * w3;
    }
  }
  float bh = b_hid[r];
#pragma unroll
  for (int bb = 0; bb < 8; ++bb) hred[bb * 256 + r] = fmaxf(acc[bb] + bh, 0.f);
  __syncthreads();

  const int wv = tid >> 6, l = tid & 63;
  float wo0 = w_out[0 * 256 + r], wo1 = w_out[1 * 256 + r], wo2 = w_out[2 * 256 + r];
#pragma unroll 1
  for (int bb = 0; bb < 8; ++bb) {
    float h = hred[bb * 256 + r];
    float p0 = h * wo0, p1 = h * wo1, p2 = h * wo2;
#pragma unroll
    for (int off = 32; off > 0; off >>= 1) {
      p0 += __shfl_down(p0, off, 64);
      p1 += __shfl_down(p1, off, 64);
      p2 += __shfl_down(p2, off, 64);
    }
    if (l == 0) {
      pred[wv * 24 + bb * 3 + 0] = p0;
      pred[wv * 24 + bb * 3 + 1] = p1;
      pred[wv * 24 + bb * 3 + 2] = p2;
    }
  }
  __syncthreads();
  if (tid < 24) {
    int bb = tid / 3, o = tid % 3;
    float s = pred[0 * 24 + tid] + pred[1 * 24 + tid] + pred[2 * 24 + tid] + pred[3 * 24 + tid]
              + b_out[o];
    out[(size_t)(b0 + bb) * 3 + o] = s;
  }
}

// ============================================================================
extern "C" void kernel_launch(void* const* d_in, const int* in_sizes, int n_in,
                              void* d_out, int out_size, void* d_ws, size_t ws_size,
                              hipStream_t stream) {
  (void)in_sizes; (void)n_in; (void)out_size; (void)ws_size; // needs ~105 MB ws
  const int*   s1    = (const int*)d_in[0];
  const int*   s2    = (const int*)d_in[1];
  const float* emb   = (const float*)d_in[2];
  const float* w_ih  = (const float*)d_in[3];
  const float* w_hh  = (const float*)d_in[4];
  const float* b_ih  = (const float*)d_in[5];
  const float* b_hh  = (const float*)d_in[6];
  const float* w_hid = (const float*)d_in[7];
  const float* b_hid = (const float*)d_in[8];
  const float* w_out = (const float*)d_in[9];
  const float* b_out = (const float*)d_in[10];
  char* ws = (char*)d_ws;
  unsigned short* table2 = (unsigned short*)(ws + OFF_TABLE);
  unsigned short* whhf   = (unsigned short*)(ws + OFF_WHHF);
  unsigned short* wihf   = (unsigned short*)(ws + OFF_WIHF);
  float* bcomb = (float*)(ws + OFF_BCOMB);
  float* whidT = (float*)(ws + OFF_WHIDT);
  float* h_out = (float*)(ws + OFF_HOUT);
  float* outp  = (float*)d_out;

  k0_prep<<<dim3(2052), dim3(256), 0, stream>>>(w_ih, w_hh, b_ih, b_hh, w_hid,
                                                whhf, wihf, bcomb, whidT);
  k1_table<<<dim3(782), dim3(256), 0, stream>>>(emb, wihf, bcomb, table2);
  k2_lstm<<<dim3(128), dim3(512), 0, stream>>>(s1, s2, table2, whhf, h_out);
  k3_head<<<dim3(64), dim3(256), 0, stream>>>(h_out, whidT, b_hid, w_out, b_out, outp);
}

// Round 7
// 1361.527 us; speedup vs baseline: 1.6412x; 1.6412x over previous
//
#include <hip/hip_runtime.h>
#include <stdint.h>
#include <stddef.h>

// Problem constants
#define VOCAB 50000
#define EMB   128
#define HID   256
#define G4    1024   // 4*HID
#define BATCH 512
#define SEQ   256
#define NCHAIN 1024  // 2 sequences * 512 batch

// ---------- workspace layout (bytes) ----------
#define OFF_TABLE  0UL
#define SZ_TABLE   (50000UL*1024UL*2UL)            // 102,400,000  bf16 gate table (permuted cols)
#define OFF_WHHF   (OFF_TABLE + SZ_TABLE)
#define SZ_WHHF    (512UL*512UL*2UL)               // 524,288      w_hh B-fragments bf16
#define OFF_WIHF   (OFF_WHHF + SZ_WHHF)
#define SZ_WIHF    (256UL*512UL*2UL)               // 262,144      w_ih B-fragments bf16
#define OFF_BCOMB  (OFF_WIHF + SZ_WIHF)
#define SZ_BCOMB   (1024UL*4UL)                    // combined bias (permuted)
#define OFF_WHIDT  (OFF_BCOMB + SZ_BCOMB)
#define SZ_WHIDT   (512UL*256UL*4UL)               // w_hid transposed [512][256] f32
#define OFF_HOUT   (OFF_WHIDT + SZ_WHIDT)
#define SZ_HOUT    (1024UL*256UL*4UL)              // final h per chain, f32
// total ~104.8 MB

typedef short bf16x8 __attribute__((ext_vector_type(8)));
typedef short bf16x4 __attribute__((ext_vector_type(4)));
typedef float f32x4  __attribute__((ext_vector_type(4)));
typedef float f32x2  __attribute__((ext_vector_type(2)));

__device__ __forceinline__ unsigned short f2bf(float f) {
  union { float f; uint32_t u; } v; v.f = f;
  uint32_t r = (v.u + 0x7FFFu + ((v.u >> 16) & 1u)) >> 16;
  return (unsigned short)r;
}
__device__ __forceinline__ float bf2f(unsigned short h) {
  union { float f; uint32_t u; } v; v.u = ((uint32_t)h) << 16; return v.f;
}
__device__ __forceinline__ float fast_exp2(float x) { return __builtin_amdgcn_exp2f(x); }
__device__ __forceinline__ float fast_rcp(float x)  { return __builtin_amdgcn_rcpf(x); }
#define LOG2E 1.4426950408889634f
__device__ __forceinline__ float sigm(float x) {
  return fast_rcp(1.0f + fast_exp2(-LOG2E * x));
}
__device__ __forceinline__ float tanh_(float x) {
  float e = fast_exp2(2.0f * LOG2E * x);     // exp(2x)
  return 1.0f - 2.0f * fast_rcp(e + 1.0f);   // (e-1)/(e+1)
}

// gate permutation: wave w (0..7) owns local gates i (0..127);
// original gate index = (i>>5)*256 + w*32 + (i&31)   (blocks: i,f,g,o for j in [w*32, w*32+32))
__device__ __forceinline__ int gperm(int w, int i) {
  return ((i >> 5) << 8) + (w << 5) + (i & 31);
}

// LDS swizzles (byte-XOR per G4 to break b128 same-bank columns). Index in ushorts.
__device__ __forceinline__ int hswz(int m, int k) {          // h tile: row stride 256 bf16
  return ((m * 512 + k * 2) ^ ((m & 7) << 4)) >> 1;
}
__device__ __forceinline__ int aswz(int row, int k) {        // emb tile: row stride 128 bf16
  return ((row * 256 + k * 2) ^ ((row & 7) << 4)) >> 1;
}

// Shared A/B k-placement bijection within each 32-wide k block (A and B use the SAME
// map so the MFMA contraction pairs identical true-k on both sides; dot products are
// permutation-invariant so the true HW k-map is irrelevant):
//   scatter by true k: k = hf*16 + v (hf=bit4, v=k&15) -> p = (v>>2)*8 + hf*4 + (v&3)
__device__ __forceinline__ int kplace(int k) {   // k in [0,32), returns p in [0,32)
  int v = k & 15, hf = (k >> 4) & 1;
  return ((v >> 2) << 3) + (hf << 2) + (v & 3);
}

// xg table column order within wave slice: storage pos = c0*8 + nt (nt = local n-tile
// = gate*2 + hf). k2's lane (r0,c0) reads ONE b128 per chain directly from global
// (positions [c0*8, c0*8+8) = all 8 nt for its c0) -- no LDS staging, compile-time
// extracts xv[gate*2+hf]. (R6 lesson: runtime register indexing = rule-#20 disaster.)

// ============================================================================
// k0: pack w_hh / w_ih into MFMA B-fragment layout (bf16), combined bias, w_hid^T
// ============================================================================
__global__ __launch_bounds__(256) void k0_prep(
    const float* __restrict__ w_ih, const float* __restrict__ w_hh,
    const float* __restrict__ b_ih, const float* __restrict__ b_hh,
    const float* __restrict__ w_hid,
    unsigned short* __restrict__ whhf, unsigned short* __restrict__ wihf,
    float* __restrict__ bcomb, float* __restrict__ whidT)
{
  int idx = blockIdx.x * 256 + threadIdx.x;
  if (idx < 262144) {                       // whhf: 512 frags x 512 ushorts
    int f = idx >> 9, r = idx & 511, l = r >> 3, e = r & 7;
    int w = f >> 6, nt = (f >> 3) & 7, ks = f & 7;
    int n = gperm(w, nt * 16 + (l & 15));
    int k = ks * 32 + ((e >> 2) << 4) + ((l >> 4) << 2) + (e & 3);
    whhf[idx] = f2bf(w_hh[n * HID + k]);
  } else if (idx < 262144 + 131072) {       // wihf: 256 frags x 512
    int i2 = idx - 262144;
    int f = i2 >> 9, r = i2 & 511, l = r >> 3, e = r & 7;
    int ks = f & 3, nt = (f >> 2) & 7, w = f >> 5;
    int n = gperm(w, nt * 16 + (l & 15));
    int k = ks * 32 + ((e >> 2) << 4) + ((l >> 4) << 2) + (e & 3);
    wihf[i2] = f2bf(w_ih[n * EMB + k]);
  } else if (idx < 262144 + 131072 + 1024) {
    int i2 = idx - (262144 + 131072);
    int w = i2 >> 7, ii = i2 & 127;
    int g = gperm(w, ii);
    bcomb[i2] = b_ih[g] + b_hh[g];
  } else if (idx < 262144 + 131072 + 1024 + 131072) {
    int i2 = idx - (262144 + 131072 + 1024);
    int k = i2 >> 8, rr = i2 & 255;
    whidT[i2] = w_hid[rr * 512 + k];        // w_hid [256][512] -> [512][256]
  }
}

// ============================================================================
// k1: gate table GEMM: table[v][p] = emb[v] . w_ih[G(p)] + bcomb[p]   (bf16 out)
//     M=50000 rows (64/block), N=1024 permuted cols, K=128.
// ============================================================================
__global__ __launch_bounds__(256, 4) void k1_table(
    const float* __restrict__ emb, const unsigned short* __restrict__ wihf,
    const float* __restrict__ bcomb, unsigned short* __restrict__ table2)
{
  __shared__ unsigned short a_lds[64 * 128];      // swizzled + k-placed bf16
  __shared__ unsigned short ostage[4 * 16 * 136]; // per-wave staging, padded rows
  const int tid = threadIdx.x;
  const int w = tid >> 6, l = tid & 63, r0 = l >> 4, c0 = l & 15;
  const int v0 = blockIdx.x * 64;

  // stage 64 emb rows as bf16, scattered into the SHARED k-placement map
  for (int idx = tid; idx < 8192; idx += 256) {
    int row = idx >> 7, k = idx & 127;
    int gr = v0 + row; if (gr >= VOCAB) gr = VOCAB - 1;
    float x = emb[(size_t)gr * EMB + k];
    int p = (k & ~31) + kplace(k & 31);
    a_lds[aswz(row, p)] = f2bf(x);
  }
  __syncthreads();

  bf16x8 af[4];
#pragma unroll
  for (int ks = 0; ks < 4; ++ks)
    af[ks] = *(const bf16x8*)&a_lds[aswz(w * 16 + c0, ks * 32 + r0 * 8)];

  unsigned short* ost = &ostage[w * 2176];
#pragma unroll 1
  for (int nb = 0; nb < 8; ++nb) {
    f32x4 acc[8];
#pragma unroll
    for (int nt = 0; nt < 8; ++nt) acc[nt] = (f32x4){0.f, 0.f, 0.f, 0.f};
#pragma unroll
    for (int ks = 0; ks < 4; ++ks) {
#pragma unroll
      for (int nt = 0; nt < 8; ++nt) {
        bf16x8 bv = *(const bf16x8*)(wihf + ((((nb * 8 + nt) * 4) + ks) << 9) + (l << 3));
        acc[nt] = __builtin_amdgcn_mfma_f32_16x16x32_bf16(af[ks], bv, acc[nt], 0, 0, 0);
      }
    }
    // column order: local gate (nt,c0) stored at pos c0*8 + nt
#pragma unroll
    for (int nt = 0; nt < 8; ++nt) {
      float bias = bcomb[nb * 128 + nt * 16 + c0];
#pragma unroll
      for (int reg = 0; reg < 4; ++reg)
        ost[(r0 * 4 + reg) * 136 + c0 * 8 + nt] = f2bf(acc[nt][reg] + bias);
    }
    asm volatile("s_waitcnt lgkmcnt(0)" ::: "memory");
#pragma unroll
    for (int i = 0; i < 4; ++i) {
      int idx = i * 64 + l;
      int row = idx >> 4, seg = idx & 15;
      int v = v0 + w * 16 + row;
      if (v < VOCAB)
        *(bf16x8*)(table2 + (size_t)v * 1024 + nb * 128 + seg * 8) =
            *(const bf16x8*)&ost[row * 136 + seg * 8];
    }
    __syncthreads();
  }
}

// ============================================================================
// k2: the recurrence. 64 blocks x 512 threads (8 waves). Block owns 16 chains.
//     Wave w owns gates {i,f,g,o} for j in [w*32, w*32+32) = 8 n-tiles of 16.
//     Structure (R7):
//       - h DOUBLE-buffered in LDS -> ONE barrier per step (read buf[t&1],
//         write buf[(t+1)&1]; end-of-step barrier covers both hazards).
//       - xg: NO LDS staging. Lane (r0,c0) gathers one b128 per chain
//         (4 chains = rows r0*4+q) at column c0*8 -> its exact 8 gate
//         pre-activations, xv[gate*2+hf] extracts all compile-time.
//         Gather issued at END of step t-1 (cover = barrier + MFMA loop).
//       - weights: nt0..3 reg-resident (128 regs), nt4..5 LDS-resident
//         (128 KB), nt6..7 streamed from L2 (16 KB/wave/step, 3-slot
//         rotating buffer, 2-ks lookahead).
// ============================================================================
__global__ __launch_bounds__(512) void k2_lstm(
    const int* __restrict__ s1, const int* __restrict__ s2,
    const unsigned short* __restrict__ table2,
    const unsigned short* __restrict__ whhf,
    float* __restrict__ h_out)
{
  __shared__ unsigned short h_lds[2][16 * 256];   // 16 KB dbuf, swizzled+k-placed
  __shared__ unsigned short tok_lds[16 * 256];    // 8 KB tokens u16
  __shared__ unsigned short w_lds[8][16 * 512];   // 128 KB: per wave nt4,nt5 all ks

  const int tid = threadIdx.x;
  const int w = tid >> 6, l = tid & 63;
  const int r0 = l >> 4, c0 = l & 15;
  const int blk = blockIdx.x;

  // preload tokens (u16) + zero h buf0
  for (int idx = tid; idx < 4096; idx += 512) {
    int chain = blk * 16 + (idx >> 8);
    const int* sp = (chain >= 512) ? s2 : s1;
    tok_lds[idx] = (unsigned short)sp[(chain & 511) * SEQ + (idx & 255)];
    h_lds[0][idx] = 0;
  }

  const unsigned short* whW = whhf + w * 32768;  // this wave's 64 frags
  unsigned short* wl = w_lds[w];

  // LDS-resident frags: j = (nt-4)*8 + ks for nt 4..5
#pragma unroll
  for (int j = 0; j < 16; ++j) {
    bf16x8 v = *(const bf16x8*)(whW + ((32 + j) << 9) + (l << 3));
    *(bf16x8*)&wl[j * 512 + (l << 3)] = v;
  }

  // VGPR/AGPR-resident frags: nt 0..3, all ks (128 regs)
  bf16x8 whr[32];
#pragma unroll
  for (int f = 0; f < 32; ++f)
    whr[f] = *(const bf16x8*)(whW + (f << 9) + (l << 3));

  __syncthreads();

  // streamed rotating buffer: batch p: slot p%3 = {nt6 ksp, nt7 ksp}
  bf16x8 sbuf[3][2];
#define ISSUE_BATCH(P, S)                                                         \
  do {                                                                            \
    sbuf[S][0] = *(const bf16x8*)(whW + ((6 * 8 + (P)) << 9) + (l << 3));         \
    sbuf[S][1] = *(const bf16x8*)(whW + ((7 * 8 + (P)) << 9) + (l << 3));         \
  } while (0)

  // per-lane xg gather base: column slice [w*128 + c0*8, +8)
  const unsigned short* gbase = table2 + w * 128 + c0 * 8;

  // prologue: gather XR(t=0) for my 4 chains + first two stream batches
  bf16x8 XR0, XR1, XR2, XR3;
  {
    int ta = tok_lds[(r0 * 4 + 0) * 256 + 0];
    int tb = tok_lds[(r0 * 4 + 1) * 256 + 0];
    int tc = tok_lds[(r0 * 4 + 2) * 256 + 0];
    int td = tok_lds[(r0 * 4 + 3) * 256 + 0];
    XR0 = *(const bf16x8*)(gbase + (size_t)ta * 1024);
    XR1 = *(const bf16x8*)(gbase + (size_t)tb * 1024);
    XR2 = *(const bf16x8*)(gbase + (size_t)tc * 1024);
    XR3 = *(const bf16x8*)(gbase + (size_t)td * 1024);
  }
  ISSUE_BATCH(0, 0);
  ISSUE_BATCH(1, 1);

  float c_st[8], hv[8];
#pragma unroll
  for (int i = 0; i < 8; ++i) { c_st[i] = 0.f; hv[i] = 0.f; }

#pragma unroll 1
  for (int t = 0; t < SEQ; ++t) {
    const unsigned short* hcur = h_lds[t & 1];
    unsigned short* hnxt = h_lds[(t + 1) & 1];

    f32x4 acc[8];
#pragma unroll
    for (int nt = 0; nt < 8; ++nt) acc[nt] = (f32x4){0.f, 0.f, 0.f, 0.f};

#pragma unroll
    for (int p = 0; p < 8; ++p) {
      if (p + 2 <= 7) { ISSUE_BATCH(p + 2, (p + 2) % 3); }
      bf16x8 av = *(const bf16x8*)&hcur[hswz(c0, p * 32 + r0 * 8)];
      acc[0] = __builtin_amdgcn_mfma_f32_16x16x32_bf16(av, whr[0 * 8 + p], acc[0], 0, 0, 0);
      acc[1] = __builtin_amdgcn_mfma_f32_16x16x32_bf16(av, whr[1 * 8 + p], acc[1], 0, 0, 0);
      acc[2] = __builtin_amdgcn_mfma_f32_16x16x32_bf16(av, whr[2 * 8 + p], acc[2], 0, 0, 0);
      acc[3] = __builtin_amdgcn_mfma_f32_16x16x32_bf16(av, whr[3 * 8 + p], acc[3], 0, 0, 0);
      {
        bf16x8 bv = *(const bf16x8*)&wl[p * 512 + (l << 3)];          // nt4
        acc[4] = __builtin_amdgcn_mfma_f32_16x16x32_bf16(av, bv, acc[4], 0, 0, 0);
      }
      {
        bf16x8 bv = *(const bf16x8*)&wl[(8 + p) * 512 + (l << 3)];    // nt5
        acc[5] = __builtin_amdgcn_mfma_f32_16x16x32_bf16(av, bv, acc[5], 0, 0, 0);
      }
      acc[6] = __builtin_amdgcn_mfma_f32_16x16x32_bf16(av, sbuf[p % 3][0], acc[6], 0, 0, 0);
      acc[7] = __builtin_amdgcn_mfma_f32_16x16x32_bf16(av, sbuf[p % 3][1], acc[7], 0, 0, 0);
    }

    // gates -> c,h. All indices compile-time. xv = this lane's gathered b128
    // per chain (positions c0*8 + nt, nt = gate*2 + hf).
#pragma unroll
    for (int hf = 0; hf < 2; ++hf)
#pragma unroll
      for (int q = 0; q < 4; ++q) {
        bf16x8 xv = (q == 0) ? XR0 : (q == 1) ? XR1 : (q == 2) ? XR2 : XR3;
        float iv = sigm(acc[0 + hf][q] + bf2f((unsigned short)xv[0 + hf]));
        float fv = sigm(acc[2 + hf][q] + bf2f((unsigned short)xv[2 + hf]));
        float gv = tanh_(acc[4 + hf][q] + bf2f((unsigned short)xv[4 + hf]));
        float ov = sigm(acc[6 + hf][q] + bf2f((unsigned short)xv[6 + hf]));
        int cs = hf * 4 + q;
        float c = fv * c_st[cs] + iv * gv;
        c_st[cs] = c;
        hv[cs] = ov * tanh_(c);
      }

    // issue NEXT step's gather + first two stream batches (cover = h-write +
    // barrier + next MFMA loop)
    if (t + 1 < SEQ) {
      int ta = tok_lds[(r0 * 4 + 0) * 256 + (t + 1)];
      int tb = tok_lds[(r0 * 4 + 1) * 256 + (t + 1)];
      int tc = tok_lds[(r0 * 4 + 2) * 256 + (t + 1)];
      int td = tok_lds[(r0 * 4 + 3) * 256 + (t + 1)];
      XR0 = *(const bf16x8*)(gbase + (size_t)ta * 1024);
      XR1 = *(const bf16x8*)(gbase + (size_t)tb * 1024);
      XR2 = *(const bf16x8*)(gbase + (size_t)tc * 1024);
      XR3 = *(const bf16x8*)(gbase + (size_t)td * 1024);
      ISSUE_BATCH(0, 0);
      ISSUE_BATCH(1, 1);
    }

    // write h(t) to the OTHER buffer; reads of hcur all happened above
#pragma unroll
    for (int hf = 0; hf < 2; ++hf)
#pragma unroll
      for (int q = 0; q < 4; ++q) {
        int m = r0 * 4 + q;
        // original j = w*32 + hf*16 + c0 -> SHARED k-placement within block w
        int qk = (w << 5) + ((c0 >> 2) << 3) + (hf << 2) + (c0 & 3);
        hnxt[hswz(m, qk)] = f2bf(hv[hf * 4 + q]);
      }
    __syncthreads();   // ONE barrier: h(t) visible, hcur free for overwrite
  }

  // final h (f32, pre-rounding) -> h_out[chain][j]
#pragma unroll
  for (int hf = 0; hf < 2; ++hf)
#pragma unroll
    for (int q = 0; q < 4; ++q) {
      int m = r0 * 4 + q;
      int j = w * 32 + hf * 16 + c0;
      h_out[(size_t)(blk * 16 + m) * HID + j] = hv[hf * 4 + q];
    }
#undef ISSUE_BATCH
}

// ============================================================================
// k3: head: hidden = relu([h1,h2] @ w_hid^T + b_hid); out = hidden @ w_out^T + b_out
// ============================================================================
__global__ __launch_bounds__(256, 4) void k3_head(
    const float* __restrict__ h_out, const float* __restrict__ whidT,
    const float* __restrict__ b_hid, const float* __restrict__ w_out,
    const float* __restrict__ b_out, float* __restrict__ out)
{
  __shared__ float cat[8 * 512];
  __shared__ float hred[8 * 256];
  __shared__ float pred[4 * 24];
  const int tid = threadIdx.x;
  const int b0 = blockIdx.x * 8;

  for (int idx = tid; idx < 4096; idx += 256) {
    int r8 = idx >> 9, kk = idx & 511;
    float v = (kk < 256) ? h_out[(size_t)(b0 + r8) * HID + kk]
                         : h_out[(size_t)(512 + b0 + r8) * HID + (kk - 256)];
    cat[idx] = v;
  }
  __syncthreads();

  const int r = tid;
  float acc[8];
#pragma unroll
  for (int bb = 0; bb < 8; ++bb) acc[bb] = 0.f;
  for (int k = 0; k < 512; k += 4) {
    float w0 = whidT[(k + 0) * 256 + r];
    float w1 = whidT[(k + 1) * 256 + r];
    float w2 = whidT[(k + 2) * 256 + r];
    float w3 = whidT[(k + 3) * 256 + r];
#pragma unroll
    for (int bb = 0; bb < 8; ++bb) {
      f32x4 cv = *(const f32x4*)&cat[bb * 512 + k];
      acc[bb] += cv[0] * w0 + cv[1] * w1 + cv[2] * w2 + cv[3] * w3;
    }
  }
  float bh = b_hid[r];
#pragma unroll
  for (int bb = 0; bb < 8; ++bb) hred[bb * 256 + r] = fmaxf(acc[bb] + bh, 0.f);
  __syncthreads();

  const int wv = tid >> 6, l = tid & 63;
  float wo0 = w_out[0 * 256 + r], wo1 = w_out[1 * 256 + r], wo2 = w_out[2 * 256 + r];
#pragma unroll 1
  for (int bb = 0; bb < 8; ++bb) {
    float h = hred[bb * 256 + r];
    float p0 = h * wo0, p1 = h * wo1, p2 = h * wo2;
#pragma unroll
    for (int off = 32; off > 0; off >>= 1) {
      p0 += __shfl_down(p0, off, 64);
      p1 += __shfl_down(p1, off, 64);
      p2 += __shfl_down(p2, off, 64);
    }
    if (l == 0) {
      pred[wv * 24 + bb * 3 + 0] = p0;
      pred[wv * 24 + bb * 3 + 1] = p1;
      pred[wv * 24 + bb * 3 + 2] = p2;
    }
  }
  __syncthreads();
  if (tid < 24) {
    int bb = tid / 3, o = tid % 3;
    float s = pred[0 * 24 + tid] + pred[1 * 24 + tid] + pred[2 * 24 + tid] + pred[3 * 24 + tid]
              + b_out[o];
    out[(size_t)(b0 + bb) * 3 + o] = s;
  }
}

// ============================================================================
extern "C" void kernel_launch(void* const* d_in, const int* in_sizes, int n_in,
                              void* d_out, int out_size, void* d_ws, size_t ws_size,
                              hipStream_t stream) {
  (void)in_sizes; (void)n_in; (void)out_size; (void)ws_size; // needs ~105 MB ws
  const int*   s1    = (const int*)d_in[0];
  const int*   s2    = (const int*)d_in[1];
  const float* emb   = (const float*)d_in[2];
  const float* w_ih  = (const float*)d_in[3];
  const float* w_hh  = (const float*)d_in[4];
  const float* b_ih  = (const float*)d_in[5];
  const float* b_hh  = (const float*)d_in[6];
  const float* w_hid = (const float*)d_in[7];
  const float* b_hid = (const float*)d_in[8];
  const float* w_out = (const float*)d_in[9];
  const float* b_out = (const float*)d_in[10];
  char* ws = (char*)d_ws;
  unsigned short* table2 = (unsigned short*)(ws + OFF_TABLE);
  unsigned short* whhf   = (unsigned short*)(ws + OFF_WHHF);
  unsigned short* wihf   = (unsigned short*)(ws + OFF_WIHF);
  float* bcomb = (float*)(ws + OFF_BCOMB);
  float* whidT = (float*)(ws + OFF_WHIDT);
  float* h_out = (float*)(ws + OFF_HOUT);
  float* outp  = (float*)d_out;

  k0_prep<<<dim3(2052), dim3(256), 0, stream>>>(w_ih, w_hh, b_ih, b_hh, w_hid,
                                                whhf, wihf, bcomb, whidT);
  k1_table<<<dim3(782), dim3(256), 0, stream>>>(emb, wihf, bcomb, table2);
  k2_lstm<<<dim3(64), dim3(512), 0, stream>>>(s1, s2, table2, whhf, h_out);
  k3_head<<<dim3(64), dim3(256), 0, stream>>>(h_out, whidT, b_hid, w_out, b_out, outp);
}

// Round 8
// 922.237 us; speedup vs baseline: 2.4230x; 1.4763x over previous
//
#include <hip/hip_runtime.h>
#include <stdint.h>
#include <stddef.h>

// Problem constants
#define VOCAB 50000
#define EMB   128
#define HID   256
#define G4    1024   // 4*HID
#define BATCH 512
#define SEQ   256
#define NCHAIN 1024  // 2 sequences * 512 batch

// ---------- workspace layout (bytes) ----------
#define OFF_TABLE  0UL
#define SZ_TABLE   (50000UL*1024UL*2UL)            // 102,400,000  bf16 gate table (permuted cols)
#define OFF_WHHF   (OFF_TABLE + SZ_TABLE)
#define SZ_WHHF    (512UL*512UL*2UL)               // 524,288      w_hh B-fragments bf16 (prescaled)
#define OFF_WIHF   (OFF_WHHF + SZ_WHHF)
#define SZ_WIHF    (256UL*512UL*2UL)               // 262,144      w_ih B-fragments bf16 (prescaled)
#define OFF_BCOMB  (OFF_WIHF + SZ_WIHF)
#define SZ_BCOMB   (1024UL*4UL)                    // combined bias (permuted, prescaled)
#define OFF_WHIDT  (OFF_BCOMB + SZ_BCOMB)
#define SZ_WHIDT   (512UL*256UL*4UL)               // w_hid transposed [512][256] f32
#define OFF_HOUT   (OFF_WHIDT + SZ_WHIDT)
#define SZ_HOUT    (1024UL*256UL*4UL)              // final h per chain, f32
// total ~104.8 MB

typedef short bf16x8 __attribute__((ext_vector_type(8)));
typedef short bf16x4 __attribute__((ext_vector_type(4)));
typedef float f32x4  __attribute__((ext_vector_type(4)));
typedef float f32x2  __attribute__((ext_vector_type(2)));

__device__ __forceinline__ unsigned short f2bf(float f) {
  union { float f; uint32_t u; } v; v.f = f;
  uint32_t r = (v.u + 0x7FFFu + ((v.u >> 16) & 1u)) >> 16;
  return (unsigned short)r;
}
__device__ __forceinline__ float bf2f(unsigned short h) {
  union { float f; uint32_t u; } v; v.u = ((uint32_t)h) << 16; return v.f;
}
__device__ __forceinline__ float fast_exp2(float x) { return __builtin_amdgcn_exp2f(x); }
__device__ __forceinline__ float fast_rcp(float x)  { return __builtin_amdgcn_rcpf(x); }
#define LOG2E 1.4426950408889634f
// PRE-SCALED activations (weights/bias for gates i,f,o carry a LOG2E factor;
// gate g carries 2*LOG2E): sigm(x) = sigm_pre(x*LOG2E), tanh(x) = tanhp(2*LOG2E*x)
__device__ __forceinline__ float sigm_pre(float z) {           // 1/(1+2^-z)
  return fast_rcp(1.0f + fast_exp2(-z));
}
__device__ __forceinline__ float tanhp(float z) {              // (2^z-1)/(2^z+1)
  return 1.0f - 2.0f * fast_rcp(fast_exp2(z) + 1.0f);
}

// gate permutation: wave w (0..7) owns local gates i (0..127);
// original gate index = (i>>5)*256 + w*32 + (i&31)
__device__ __forceinline__ int gperm(int w, int i) {
  return ((i >> 5) << 8) + (w << 5) + (i & 31);
}

// LDS swizzles (byte-XOR per G4). Index in ushorts.
__device__ __forceinline__ int hswz(int m, int k) {          // h tile: row stride 256 bf16
  return ((m * 512 + k * 2) ^ ((m & 7) << 4)) >> 1;
}
__device__ __forceinline__ int aswz(int row, int k) {        // emb tile: row stride 128 bf16
  return ((row * 256 + k * 2) ^ ((row & 7) << 4)) >> 1;
}

// Shared A/B k-placement bijection (A and B use the SAME map; dot products are
// permutation-invariant so the true HW k-map is irrelevant):
__device__ __forceinline__ int kplace(int k) {   // k in [0,32), returns p in [0,32)
  int v = k & 15, hf = (k >> 4) & 1;
  return ((v >> 2) << 3) + (hf << 2) + (v & 3);
}

// ============================================================================
// k0: pack w_hh / w_ih into MFMA B-fragment layout (bf16, PRESCALED), bias, w_hid^T
// ============================================================================
__global__ __launch_bounds__(256) void k0_prep(
    const float* __restrict__ w_ih, const float* __restrict__ w_hh,
    const float* __restrict__ b_ih, const float* __restrict__ b_hh,
    const float* __restrict__ w_hid,
    unsigned short* __restrict__ whhf, unsigned short* __restrict__ wihf,
    float* __restrict__ bcomb, float* __restrict__ whidT)
{
  int idx = blockIdx.x * 256 + threadIdx.x;
  if (idx < 262144) {                       // whhf: 512 frags x 512 ushorts
    int f = idx >> 9, r = idx & 511, l = r >> 3, e = r & 7;
    int w = f >> 6, nt = (f >> 3) & 7, ks = f & 7;
    int gate = nt >> 1;
    float sc = (gate == 2) ? (2.0f * LOG2E) : LOG2E;
    int n = gperm(w, nt * 16 + (l & 15));
    int k = ks * 32 + ((e >> 2) << 4) + ((l >> 4) << 2) + (e & 3);
    whhf[idx] = f2bf(w_hh[n * HID + k] * sc);
  } else if (idx < 262144 + 131072) {       // wihf: 256 frags x 512
    int i2 = idx - 262144;
    int f = i2 >> 9, r = i2 & 511, l = r >> 3, e = r & 7;
    int ks = f & 3, nt = (f >> 2) & 7, w = f >> 5;
    int gate = nt >> 1;
    float sc = (gate == 2) ? (2.0f * LOG2E) : LOG2E;
    int n = gperm(w, nt * 16 + (l & 15));
    int k = ks * 32 + ((e >> 2) << 4) + ((l >> 4) << 2) + (e & 3);
    wihf[i2] = f2bf(w_ih[n * EMB + k] * sc);
  } else if (idx < 262144 + 131072 + 1024) {
    int i2 = idx - (262144 + 131072);
    int w = i2 >> 7, ii = i2 & 127;
    int gate = ii >> 5;
    float sc = (gate == 2) ? (2.0f * LOG2E) : LOG2E;
    int g = gperm(w, ii);
    bcomb[i2] = (b_ih[g] + b_hh[g]) * sc;
  } else if (idx < 262144 + 131072 + 1024 + 131072) {
    int i2 = idx - (262144 + 131072 + 1024);
    int k = i2 >> 8, rr = i2 & 255;
    whidT[i2] = w_hid[rr * 512 + k];        // w_hid [256][512] -> [512][256]
  }
}

// ============================================================================
// k1: gate table GEMM: table[v][p] = emb[v] . w_ih[G(p)] + bcomb[p]   (bf16 out)
// ============================================================================
__global__ __launch_bounds__(256, 4) void k1_table(
    const float* __restrict__ emb, const unsigned short* __restrict__ wihf,
    const float* __restrict__ bcomb, unsigned short* __restrict__ table2)
{
  __shared__ unsigned short a_lds[64 * 128];      // swizzled + k-placed bf16
  __shared__ unsigned short ostage[4 * 16 * 136]; // per-wave staging, padded rows
  const int tid = threadIdx.x;
  const int w = tid >> 6, l = tid & 63, r0 = l >> 4, c0 = l & 15;
  const int v0 = blockIdx.x * 64;

  for (int idx = tid; idx < 8192; idx += 256) {
    int row = idx >> 7, k = idx & 127;
    int gr = v0 + row; if (gr >= VOCAB) gr = VOCAB - 1;
    float x = emb[(size_t)gr * EMB + k];
    int p = (k & ~31) + kplace(k & 31);
    a_lds[aswz(row, p)] = f2bf(x);
  }
  __syncthreads();

  bf16x8 af[4];
#pragma unroll
  for (int ks = 0; ks < 4; ++ks)
    af[ks] = *(const bf16x8*)&a_lds[aswz(w * 16 + c0, ks * 32 + r0 * 8)];

  unsigned short* ost = &ostage[w * 2176];
#pragma unroll 1
  for (int nb = 0; nb < 8; ++nb) {
    f32x4 acc[8];
#pragma unroll
    for (int nt = 0; nt < 8; ++nt) acc[nt] = (f32x4){0.f, 0.f, 0.f, 0.f};
#pragma unroll
    for (int ks = 0; ks < 4; ++ks) {
#pragma unroll
      for (int nt = 0; nt < 8; ++nt) {
        bf16x8 bv = *(const bf16x8*)(wihf + ((((nb * 8 + nt) * 4) + ks) << 9) + (l << 3));
        acc[nt] = __builtin_amdgcn_mfma_f32_16x16x32_bf16(af[ks], bv, acc[nt], 0, 0, 0);
      }
    }
    // column order: local gate (nt,c0) stored at pos c0*8 + nt
#pragma unroll
    for (int nt = 0; nt < 8; ++nt) {
      float bias = bcomb[nb * 128 + nt * 16 + c0];
#pragma unroll
      for (int reg = 0; reg < 4; ++reg)
        ost[(r0 * 4 + reg) * 136 + c0 * 8 + nt] = f2bf(acc[nt][reg] + bias);
    }
    asm volatile("s_waitcnt lgkmcnt(0)" ::: "memory");
#pragma unroll
    for (int i = 0; i < 4; ++i) {
      int idx = i * 64 + l;
      int row = idx >> 4, seg = idx & 15;
      int v = v0 + w * 16 + row;
      if (v < VOCAB)
        *(bf16x8*)(table2 + (size_t)v * 1024 + nb * 128 + seg * 8) =
            *(const bf16x8*)&ost[row * 136 + seg * 8];
    }
    __syncthreads();
  }
}

// ============================================================================
// k2: the recurrence. 64 blocks x 512 threads (8 waves). Block owns 16 chains.
//     R8 = R7 skeleton + stall removal:
//       - sbuf stream lookahead 3 p-steps (same 3 slots; batches 0..2 of t+1
//         issued BEFORE elementwise -> cover = elementwise+write+barrier)
//       - tokens for t+1 prefetched at step START (ds+addr off gather path)
//       - explicit 2-deep av prefetch (compiler can't prove hcur/hnxt no-alias)
//       - weights/bias prescaled by LOG2E (2LOG2E for g) -> no muls in sigm/tanh
// ============================================================================
__global__ __launch_bounds__(512) void k2_lstm(
    const int* __restrict__ s1, const int* __restrict__ s2,
    const unsigned short* __restrict__ table2,
    const unsigned short* __restrict__ whhf,
    float* __restrict__ h_out)
{
  __shared__ unsigned short h_lds[2][16 * 256];   // 16 KB dbuf, swizzled+k-placed
  __shared__ unsigned short tok_lds[16 * 256];    // 8 KB tokens u16
  __shared__ unsigned short w_lds[8][16 * 512];   // 128 KB: per wave nt4,nt5 all ks

  const int tid = threadIdx.x;
  const int w = tid >> 6, l = tid & 63;
  const int r0 = l >> 4, c0 = l & 15;
  const int blk = blockIdx.x;

  // preload tokens (u16) + zero h buf0
  for (int idx = tid; idx < 4096; idx += 512) {
    int chain = blk * 16 + (idx >> 8);
    const int* sp = (chain >= 512) ? s2 : s1;
    tok_lds[idx] = (unsigned short)sp[(chain & 511) * SEQ + (idx & 255)];
    h_lds[0][idx] = 0;
  }

  const unsigned short* whW = whhf + w * 32768;  // this wave's 64 frags
  unsigned short* wl = w_lds[w];

  // LDS-resident frags: j = (nt-4)*8 + ks for nt 4..5
#pragma unroll
  for (int j = 0; j < 16; ++j) {
    bf16x8 v = *(const bf16x8*)(whW + ((32 + j) << 9) + (l << 3));
    *(bf16x8*)&wl[j * 512 + (l << 3)] = v;
  }

  // VGPR/AGPR-resident frags: nt 0..3, all ks (128 regs)
  bf16x8 whr[32];
#pragma unroll
  for (int f = 0; f < 32; ++f)
    whr[f] = *(const bf16x8*)(whW + (f << 9) + (l << 3));

  __syncthreads();

  // streamed rotating buffer: batch p: slot p%3 = {nt6 ksp, nt7 ksp}
  bf16x8 sbuf[3][2];
#define ISSUE_BATCH(P, S)                                                         \
  do {                                                                            \
    sbuf[S][0] = *(const bf16x8*)(whW + ((6 * 8 + (P)) << 9) + (l << 3));         \
    sbuf[S][1] = *(const bf16x8*)(whW + ((7 * 8 + (P)) << 9) + (l << 3));         \
  } while (0)

  // per-lane xg gather base: column slice [w*128 + c0*8, +8)
  const unsigned short* gbase = table2 + w * 128 + c0 * 8;

  // prologue: gather XR(t=0) + first three stream batches
  bf16x8 XR0, XR1, XR2, XR3;
  {
    int ta = tok_lds[(r0 * 4 + 0) * 256 + 0];
    int tb = tok_lds[(r0 * 4 + 1) * 256 + 0];
    int tc = tok_lds[(r0 * 4 + 2) * 256 + 0];
    int td = tok_lds[(r0 * 4 + 3) * 256 + 0];
    XR0 = *(const bf16x8*)(gbase + (size_t)ta * 1024);
    XR1 = *(const bf16x8*)(gbase + (size_t)tb * 1024);
    XR2 = *(const bf16x8*)(gbase + (size_t)tc * 1024);
    XR3 = *(const bf16x8*)(gbase + (size_t)td * 1024);
  }
  ISSUE_BATCH(0, 0);
  ISSUE_BATCH(1, 1);
  ISSUE_BATCH(2, 2);

  float c_st[8], hv[8];
#pragma unroll
  for (int i = 0; i < 8; ++i) { c_st[i] = 0.f; hv[i] = 0.f; }

#pragma unroll 1
  for (int t = 0; t < SEQ; ++t) {
    const unsigned short* hcur = h_lds[t & 1];
    unsigned short* hnxt = h_lds[(t + 1) & 1];

    // prefetch NEXT step's tokens early (ds latency + addr math off the path)
    int tn = (t + 1 < SEQ) ? (t + 1) : t;
    int nta = tok_lds[(r0 * 4 + 0) * 256 + tn];
    int ntb = tok_lds[(r0 * 4 + 1) * 256 + tn];
    int ntc = tok_lds[(r0 * 4 + 2) * 256 + tn];
    int ntd = tok_lds[(r0 * 4 + 3) * 256 + tn];

    f32x4 acc[8];
#pragma unroll
    for (int nt = 0; nt < 8; ++nt) acc[nt] = (f32x4){0.f, 0.f, 0.f, 0.f};

    // explicit 2-deep av prefetch
    bf16x8 avb[2];
    avb[0] = *(const bf16x8*)&hcur[hswz(c0, 0 * 32 + r0 * 8)];
#pragma unroll
    for (int p = 0; p < 8; ++p) {
      if (p + 3 <= 7) { ISSUE_BATCH(p + 3, (p + 3) % 3); }
      if (p < 7)
        avb[(p + 1) & 1] = *(const bf16x8*)&hcur[hswz(c0, (p + 1) * 32 + r0 * 8)];
      bf16x8 av = avb[p & 1];
      acc[0] = __builtin_amdgcn_mfma_f32_16x16x32_bf16(av, whr[0 * 8 + p], acc[0], 0, 0, 0);
      acc[1] = __builtin_amdgcn_mfma_f32_16x16x32_bf16(av, whr[1 * 8 + p], acc[1], 0, 0, 0);
      acc[2] = __builtin_amdgcn_mfma_f32_16x16x32_bf16(av, whr[2 * 8 + p], acc[2], 0, 0, 0);
      acc[3] = __builtin_amdgcn_mfma_f32_16x16x32_bf16(av, whr[3 * 8 + p], acc[3], 0, 0, 0);
      {
        bf16x8 bv = *(const bf16x8*)&wl[p * 512 + (l << 3)];          // nt4
        acc[4] = __builtin_amdgcn_mfma_f32_16x16x32_bf16(av, bv, acc[4], 0, 0, 0);
      }
      {
        bf16x8 bv = *(const bf16x8*)&wl[(8 + p) * 512 + (l << 3)];    // nt5
        acc[5] = __builtin_amdgcn_mfma_f32_16x16x32_bf16(av, bv, acc[5], 0, 0, 0);
      }
      acc[6] = __builtin_amdgcn_mfma_f32_16x16x32_bf16(av, sbuf[p % 3][0], acc[6], 0, 0, 0);
      acc[7] = __builtin_amdgcn_mfma_f32_16x16x32_bf16(av, sbuf[p % 3][1], acc[7], 0, 0, 0);
    }

    // issue next step's first three stream batches BEFORE elementwise
    // (cover = elementwise + h-write + barrier vs ~300cy L2 latency).
    // Slots 0..2 last consumed at p=5,6,7 of the loop above -> safe.
    if (t + 1 < SEQ) {
      ISSUE_BATCH(0, 0);
      ISSUE_BATCH(1, 1);
      ISSUE_BATCH(2, 2);
    }

    // gates -> c,h. All indices compile-time. Pre-scaled: no muls in sigm/tanh.
#pragma unroll
    for (int hf = 0; hf < 2; ++hf)
#pragma unroll
      for (int q = 0; q < 4; ++q) {
        bf16x8 xv = (q == 0) ? XR0 : (q == 1) ? XR1 : (q == 2) ? XR2 : XR3;
        float iv = sigm_pre(acc[0 + hf][q] + bf2f((unsigned short)xv[0 + hf]));
        float fv = sigm_pre(acc[2 + hf][q] + bf2f((unsigned short)xv[2 + hf]));
        float gv = tanhp(acc[4 + hf][q] + bf2f((unsigned short)xv[4 + hf]));
        float ov = sigm_pre(acc[6 + hf][q] + bf2f((unsigned short)xv[6 + hf]));
        int cs = hf * 4 + q;
        float c = fv * c_st[cs] + iv * gv;
        c_st[cs] = c;
        hv[cs] = ov * tanhp(2.0f * LOG2E * c);
      }

    // issue NEXT step's gather (XR regs now dead; tokens already in regs)
    if (t + 1 < SEQ) {
      XR0 = *(const bf16x8*)(gbase + (size_t)nta * 1024);
      XR1 = *(const bf16x8*)(gbase + (size_t)ntb * 1024);
      XR2 = *(const bf16x8*)(gbase + (size_t)ntc * 1024);
      XR3 = *(const bf16x8*)(gbase + (size_t)ntd * 1024);
    }

    // write h(t) to the OTHER buffer
#pragma unroll
    for (int hf = 0; hf < 2; ++hf)
#pragma unroll
      for (int q = 0; q < 4; ++q) {
        int m = r0 * 4 + q;
        int qk = (w << 5) + ((c0 >> 2) << 3) + (hf << 2) + (c0 & 3);
        hnxt[hswz(m, qk)] = f2bf(hv[hf * 4 + q]);
      }
    __syncthreads();   // ONE barrier: h(t) visible, hcur free for overwrite
  }

  // final h (f32, pre-rounding) -> h_out[chain][j]
#pragma unroll
  for (int hf = 0; hf < 2; ++hf)
#pragma unroll
    for (int q = 0; q < 4; ++q) {
      int m = r0 * 4 + q;
      int j = w * 32 + hf * 16 + c0;
      h_out[(size_t)(blk * 16 + m) * HID + j] = hv[hf * 4 + q];
    }
#undef ISSUE_BATCH
}

// ============================================================================
// k3: head: hidden = relu([h1,h2] @ w_hid^T + b_hid); out = hidden @ w_out^T + b_out
// ============================================================================
__global__ __launch_bounds__(256, 4) void k3_head(
    const float* __restrict__ h_out, const float* __restrict__ whidT,
    const float* __restrict__ b_hid, const float* __restrict__ w_out,
    const float* __restrict__ b_out, float* __restrict__ out)
{
  __shared__ float cat[8 * 512];
  __shared__ float hred[8 * 256];
  __shared__ float pred[4 * 24];
  const int tid = threadIdx.x;
  const int b0 = blockIdx.x * 8;

  for (int idx = tid; idx < 4096; idx += 256) {
    int r8 = idx >> 9, kk = idx & 511;
    float v = (kk < 256) ? h_out[(size_t)(b0 + r8) * HID + kk]
                         : h_out[(size_t)(512 + b0 + r8) * HID + (kk - 256)];
    cat[idx] = v;
  }
  __syncthreads();

  const int r = tid;
  float acc[8];
#pragma unroll
  for (int bb = 0; bb < 8; ++bb) acc[bb] = 0.f;
  for (int k = 0; k < 512; k += 4) {
    float w0 = whidT[(k + 0) * 256 + r];
    float w1 = whidT[(k + 1) * 256 + r];
    float w2 = whidT[(k + 2) * 256 + r];
    float w3 = whidT[(k + 3) * 256 + r];
#pragma unroll
    for (int bb = 0; bb < 8; ++bb) {
      f32x4 cv = *(const f32x4*)&cat[bb * 512 + k];
      acc[bb] += cv[0] * w0 + cv[1] * w1 + cv[2] * w2 + cv[3] * w3;
    }
  }
  float bh = b_hid[r];
#pragma unroll
  for (int bb = 0; bb < 8; ++bb) hred[bb * 256 + r] = fmaxf(acc[bb] + bh, 0.f);
  __syncthreads();

  const int wv = tid >> 6, l = tid & 63;
  float wo0 = w_out[0 * 256 + r], wo1 = w_out[1 * 256 + r], wo2 = w_out[2 * 256 + r];
#pragma unroll 1
  for (int bb = 0; bb < 8; ++bb) {
    float h = hred[bb * 256 + r];
    float p0 = h * wo0, p1 = h * wo1, p2 = h * wo2;
#pragma unroll
    for (int off = 32; off > 0; off >>= 1) {
      p0 += __shfl_down(p0, off, 64);
      p1 += __shfl_down(p1, off, 64);
      p2 += __shfl_down(p2, off, 64);
    }
    if (l == 0) {
      pred[wv * 24 + bb * 3 + 0] = p0;
      pred[wv * 24 + bb * 3 + 1] = p1;
      pred[wv * 24 + bb * 3 + 2] = p2;
    }
  }
  __syncthreads();
  if (tid < 24) {
    int bb = tid / 3, o = tid % 3;
    float s = pred[0 * 24 + tid] + pred[1 * 24 + tid] + pred[2 * 24 + tid] + pred[3 * 24 + tid]
              + b_out[o];
    out[(size_t)(b0 + bb) * 3 + o] = s;
  }
}

// ============================================================================
extern "C" void kernel_launch(void* const* d_in, const int* in_sizes, int n_in,
                              void* d_out, int out_size, void* d_ws, size_t ws_size,
                              hipStream_t stream) {
  (void)in_sizes; (void)n_in; (void)out_size; (void)ws_size; // needs ~105 MB ws
  const int*   s1    = (const int*)d_in[0];
  const int*   s2    = (const int*)d_in[1];
  const float* emb   = (const float*)d_in[2];
  const float* w_ih  = (const float*)d_in[3];
  const float* w_hh  = (const float*)d_in[4];
  const float* b_ih  = (const float*)d_in[5];
  const float* b_hh  = (const float*)d_in[6];
  const float* w_hid = (const float*)d_in[7];
  const float* b_hid = (const float*)d_in[8];
  const float* w_out = (const float*)d_in[9];
  const float* b_out = (const float*)d_in[10];
  char* ws = (char*)d_ws;
  unsigned short* table2 = (unsigned short*)(ws + OFF_TABLE);
  unsigned short* whhf   = (unsigned short*)(ws + OFF_WHHF);
  unsigned short* wihf   = (unsigned short*)(ws + OFF_WIHF);
  float* bcomb = (float*)(ws + OFF_BCOMB);
  float* whidT = (float*)(ws + OFF_WHIDT);
  float* h_out = (float*)(ws + OFF_HOUT);
  float* outp  = (float*)d_out;

  k0_prep<<<dim3(2052), dim3(256), 0, stream>>>(w_ih, w_hh, b_ih, b_hh, w_hid,
                                                whhf, wihf, bcomb, whidT);
  k1_table<<<dim3(782), dim3(256), 0, stream>>>(emb, wihf, bcomb, table2);
  k2_lstm<<<dim3(64), dim3(512), 0, stream>>>(s1, s2, table2, whhf, h_out);
  k3_head<<<dim3(64), dim3(256), 0, stream>>>(h_out, whidT, b_hid, w_out, b_out, outp);
}